// Round 2
// baseline (250.565 us; speedup 1.0000x reference)
//
#include <hip/hip_runtime.h>

// RWKV-7 DPLR single-step decode: B=64, H=32, K=V=128, fp32.
// Per (b,h): s = a^T H0 ; t = (q*g)^T H0 ; alpha=q.b ; beta=q.k
//            o = t + alpha*s + beta*v ; Ht = diag(g)H0 + b s^T + k v^T
//
// Round-2 structure: 4096 blocks = 2048 (b,h) x 2 column-halves of 64 cols.
// Thread owns 8 rows x 4 cols of H in registers (8 x float4 = 32 VGPRs) so
// the compiler can truly keep H live across the reduction (round-1's 16 x
// float4 exceeded the 52-VGPR allocation -> loads were serialized).
// Row-partial s/t reduction: 2 shfl_xor stages in-wave, then tiny LDS.

#define KD 128
#define VD 128
#define BH_TOTAL 2048   // B*H

__global__ __launch_bounds__(256, 4) void dplr_decode_t1_kernel(
    const float* __restrict__ q_,  const float* __restrict__ k_,
    const float* __restrict__ v_,  const float* __restrict__ a_,
    const float* __restrict__ b_,  const float* __restrict__ gk_,
    const float* __restrict__ h0_, float* __restrict__ out_)
{
    const int bh   = blockIdx.x >> 1;        // 0..2047
    const int cb   = (blockIdx.x & 1) * 64;  // column-half base: 0 or 64
    const int tid  = threadIdx.x;            // 0..255
    const int c    = (tid & 15) * 4;         // local col 0..60 (x4)
    const int col  = cb + c;                 // global col
    const int grp  = tid >> 4;               // row group 0..15
    const int r0   = grp * 8;                // row base
    const int wv   = tid >> 6;               // wave 0..3

    const size_t vec_off = (size_t)bh * KD;
    const size_t h_off   = (size_t)bh * (KD * VD);

    __shared__ float qs[KD], ks_[KD], bs[KD], as_[KD], gs[KD], qgs[KD];
    __shared__ float sred[4][64];
    __shared__ float tred[4][64];
    __shared__ float scomb[64];
    __shared__ float red2[2];                // [0]=alpha, [1]=beta

    // ---- prefetch my H chunk + v slice (overlaps LDS staging) ----
    float4 Hreg[8];
    const float* hp = h0_ + h_off + (size_t)r0 * VD + col;
#pragma unroll
    for (int j = 0; j < 8; ++j)
        Hreg[j] = *(const float4*)(hp + (size_t)j * VD);
    const float4 v4 = *(const float4*)(v_ + vec_off + col);

    // ---- stage small per-(b,h) vectors into LDS ----
    if (tid < KD) {
        float qq = q_[vec_off + tid];
        float gg = __expf(gk_[vec_off + tid]);
        qs[tid]  = qq;
        ks_[tid] = k_[vec_off + tid];
        bs[tid]  = b_[vec_off + tid];
        as_[tid] = a_[vec_off + tid];
        gs[tid]  = gg;
        qgs[tid] = qq * gg;
    }
    __syncthreads();

    // ---- alpha = q.b (wave 0), beta = q.k (wave 1) ----
    if (tid < 64) {
        float p = qs[tid] * bs[tid] + qs[tid + 64] * bs[tid + 64];
#pragma unroll
        for (int o = 32; o > 0; o >>= 1) p += __shfl_down(p, o, 64);
        if (tid == 0) red2[0] = p;
    } else if (tid < 128) {
        int l = tid - 64;
        float p = qs[l] * ks_[l] + qs[l + 64] * ks_[l + 64];
#pragma unroll
        for (int o = 32; o > 0; o >>= 1) p += __shfl_down(p, o, 64);
        if (l == 0) red2[1] = p;
    }

    // ---- partial s/t over my 8 rows (LDS broadcasts are conflict-free) ----
    float4 sp = make_float4(0.f, 0.f, 0.f, 0.f);
    float4 tp = make_float4(0.f, 0.f, 0.f, 0.f);
#pragma unroll
    for (int j = 0; j < 8; ++j) {
        const float av = as_[r0 + j];
        const float qg = qgs[r0 + j];
        const float4 h = Hreg[j];
        sp.x += av * h.x; sp.y += av * h.y; sp.z += av * h.z; sp.w += av * h.w;
        tp.x += qg * h.x; tp.y += qg * h.y; tp.z += qg * h.z; tp.w += qg * h.w;
    }

    // ---- in-wave reduce over the 4 row-groups sharing this column ----
#pragma unroll
    for (int o = 16; o <= 32; o <<= 1) {
        sp.x += __shfl_xor(sp.x, o, 64); sp.y += __shfl_xor(sp.y, o, 64);
        sp.z += __shfl_xor(sp.z, o, 64); sp.w += __shfl_xor(sp.w, o, 64);
        tp.x += __shfl_xor(tp.x, o, 64); tp.y += __shfl_xor(tp.y, o, 64);
        tp.z += __shfl_xor(tp.z, o, 64); tp.w += __shfl_xor(tp.w, o, 64);
    }
    if ((tid & 63) < 16) {
        *(float4*)&sred[wv][c] = sp;
        *(float4*)&tred[wv][c] = tp;
    }
    __syncthreads();

    // ---- combine 4 wave-partials; write my 64-col slice of o ----
    if (tid < 64) {
        float sc = sred[0][tid] + sred[1][tid] + sred[2][tid] + sred[3][tid];
        float tc = tred[0][tid] + tred[1][tid] + tred[2][tid] + tred[3][tid];
        scomb[tid] = sc;
        const float vv = v_[vec_off + cb + tid];
        out_[(size_t)bh * VD + cb + tid] = tc + red2[0] * sc + red2[1] * vv;
    }
    __syncthreads();

    // ---- Ht = g*H + b s^T + k v^T, from registers ----
    const float4 s4 = *(const float4*)&scomb[c];
    float* op = out_ + (size_t)BH_TOTAL * VD + h_off + (size_t)r0 * VD + col;
#pragma unroll
    for (int j = 0; j < 8; ++j) {
        const int r = r0 + j;
        const float gr = gs[r];
        const float br = bs[r];
        const float kr = ks_[r];
        const float4 h = Hreg[j];
        float4 o4;
        o4.x = gr * h.x + br * s4.x + kr * v4.x;
        o4.y = gr * h.y + br * s4.y + kr * v4.y;
        o4.z = gr * h.z + br * s4.z + kr * v4.z;
        o4.w = gr * h.w + br * s4.w + kr * v4.w;
        *(float4*)(op + (size_t)j * VD) = o4;
    }
}

extern "C" void kernel_launch(void* const* d_in, const int* in_sizes, int n_in,
                              void* d_out, int out_size, void* d_ws, size_t ws_size,
                              hipStream_t stream) {
    const float* q  = (const float*)d_in[0];
    const float* k  = (const float*)d_in[1];
    const float* v  = (const float*)d_in[2];
    const float* a  = (const float*)d_in[3];
    const float* b  = (const float*)d_in[4];
    const float* gk = (const float*)d_in[5];
    const float* h0 = (const float*)d_in[6];
    float* out = (float*)d_out;

    dplr_decode_t1_kernel<<<BH_TOTAL * 2, 256, 0, stream>>>(q, k, v, a, b, gk, h0, out);
}